// Round 6
// baseline (552.153 us; speedup 1.0000x reference)
//
#include <hip/hip_runtime.h>
#include <hip/hip_bf16.h>

typedef short short8 __attribute__((ext_vector_type(8)));
typedef float floatx4 __attribute__((ext_vector_type(4)));
typedef unsigned short ushort_t;
typedef unsigned short ushort4v __attribute__((ext_vector_type(4)));

__device__ __forceinline__ ushort_t f2bf(float v) {
    __hip_bfloat16 h = __float2bfloat16(v);
    return *(ushort_t*)&h;
}
__device__ __forceinline__ float bf2f(ushort_t u) {
    return __uint_as_float(((unsigned)u) << 16);
}
__device__ __forceinline__ float4 ldh4(const ushort_t* p) {
    ushort4v u = *(const ushort4v*)p;
    return make_float4(bf2f(u.x), bf2f(u.y), bf2f(u.z), bf2f(u.w));
}

// ---------------- x split: x[N,K] fp32 -> xhi/xlo[N,K] bf16 ----------------
__global__ __launch_bounds__(256) void xsplit_kernel(const float* __restrict__ X,
                                                     ushort_t* __restrict__ Xhi,
                                                     ushort_t* __restrict__ Xlo, int total) {
    int idx = blockIdx.x * 256 + threadIdx.x;
    if (idx >= total) return;
    float v = X[idx];
    ushort_t h = f2bf(v);
    Xhi[idx] = h;
    Xlo[idx] = f2bf(v - bf2f(h));
}

// ---------------- W pre-transpose + split: W[K][256] fp32 -> Bt{hi,lo}[256][K] bf16 ----------------
__global__ __launch_bounds__(256) void wsplit_kernel(const float* __restrict__ W,
                                                     ushort_t* __restrict__ Bthi,
                                                     ushort_t* __restrict__ Btlo, int K) {
    int idx = blockIdx.x * 256 + threadIdx.x;
    if (idx >= K * 256) return;
    int n = idx & 255, k = idx >> 8;
    float v = W[(size_t)k * 256 + n];
    ushort_t h = f2bf(v);
    float r = v - bf2f(h);
    Bthi[(size_t)n * K + k] = h;
    Btlo[(size_t)n * K + k] = f2bf(r);
}

// ---------------- MFMA split-bf16 GEMM: H[N,256](bf16) = (Ahi+Alo) @ (Whi+Wlo) ------------------
// A pre-split bf16 in global (K-contiguous rows). 128x128 tile, 4 waves, BK=32, 3-term MFMA.
// LDS stride 36 ushorts: fragment b128 reads hit 16 distinct banks (conflict-free).
// Epilogue: bf16 H store + fused alpha dot products (fp32, shuffle + atomics).
#define LSTR 36
__global__ __launch_bounds__(256, 4) void gemm_mfma(const ushort_t* __restrict__ Ahi_g,
                                                    const ushort_t* __restrict__ Alo_g,
                                                    const ushort_t* __restrict__ Bthi,
                                                    const ushort_t* __restrict__ Btlo,
                                                    ushort_t* __restrict__ Hb,
                                                    const float* __restrict__ a_src,
                                                    const float* __restrict__ a_dst,
                                                    float* __restrict__ asrc_out,
                                                    float* __restrict__ adst_out,
                                                    int N, int K) {
    __shared__ ushort_t Ahi[128 * LSTR];
    __shared__ ushort_t Alo[128 * LSTR];
    __shared__ ushort_t Bhi[128 * LSTR];
    __shared__ ushort_t Blo[128 * LSTR];

    const int tid = threadIdx.x;
    const int wave = tid >> 6, lane = tid & 63;
    const int wr = wave & 1, wc = wave >> 1;     // wave row / col within 2x2
    const int q = lane >> 4, l15 = lane & 15;
    const int rowBase = blockIdx.x * 128;
    const int colBase = blockIdx.y * 128;

    floatx4 acc[4][4];
#pragma unroll
    for (int i = 0; i < 4; ++i)
#pragma unroll
        for (int j = 0; j < 4; ++j) acc[i][j] = (floatx4)0.f;

    const int a_row = tid >> 1;          // 0..127
    const int a_k0  = (tid & 1) * 16;    // 0 or 16
    const short8 zero8 = (short8)0;

    for (int kc = 0; kc < K; kc += 32) {
        // ---- stage A tile (pre-split bf16 copy) ----
        {
            int grow = rowBase + a_row;
            int base = a_row * LSTR + a_k0;
            if (grow < N) {
                const ushort_t* ah = Ahi_g + (size_t)grow * K + kc + a_k0;
                const ushort_t* al = Alo_g + (size_t)grow * K + kc + a_k0;
                *(short8*)&Ahi[base + 0] = *(const short8*)(ah + 0);
                *(short8*)&Ahi[base + 8] = *(const short8*)(ah + 8);
                *(short8*)&Alo[base + 0] = *(const short8*)(al + 0);
                *(short8*)&Alo[base + 8] = *(const short8*)(al + 8);
            } else {
                *(short8*)&Ahi[base + 0] = zero8;
                *(short8*)&Ahi[base + 8] = zero8;
                *(short8*)&Alo[base + 0] = zero8;
                *(short8*)&Alo[base + 8] = zero8;
            }
        }
        // ---- stage B tile (pre-split bf16 copy) ----
        {
            const ushort_t* bh = Bthi + (size_t)(colBase + a_row) * K + kc + a_k0;
            const ushort_t* bl = Btlo + (size_t)(colBase + a_row) * K + kc + a_k0;
            int base = a_row * LSTR + a_k0;
            *(short8*)&Bhi[base + 0] = *(const short8*)(bh + 0);
            *(short8*)&Bhi[base + 8] = *(const short8*)(bh + 8);
            *(short8*)&Blo[base + 0] = *(const short8*)(bl + 0);
            *(short8*)&Blo[base + 8] = *(const short8*)(bl + 8);
        }
        __syncthreads();

        short8 afh[4], afl[4], bfh[4], bfl[4];
#pragma unroll
        for (int mt = 0; mt < 4; ++mt) {
            int r = wr * 64 + mt * 16 + l15;
            afh[mt] = *(short8*)&Ahi[r * LSTR + q * 8];
            afl[mt] = *(short8*)&Alo[r * LSTR + q * 8];
        }
#pragma unroll
        for (int nt = 0; nt < 4; ++nt) {
            int n = wc * 64 + nt * 16 + l15;
            bfh[nt] = *(short8*)&Bhi[n * LSTR + q * 8];
            bfl[nt] = *(short8*)&Blo[n * LSTR + q * 8];
        }
#pragma unroll
        for (int mt = 0; mt < 4; ++mt)
#pragma unroll
            for (int nt = 0; nt < 4; ++nt) {
                acc[mt][nt] = __builtin_amdgcn_mfma_f32_16x16x32_bf16(afh[mt], bfh[nt], acc[mt][nt], 0, 0, 0);
                acc[mt][nt] = __builtin_amdgcn_mfma_f32_16x16x32_bf16(afh[mt], bfl[nt], acc[mt][nt], 0, 0, 0);
                acc[mt][nt] = __builtin_amdgcn_mfma_f32_16x16x32_bf16(afl[mt], bfh[nt], acc[mt][nt], 0, 0, 0);
            }
        __syncthreads();
    }

    // ---- epilogue: bf16 H store + fused alpha (fp32) ----
    float asv[4], adv[4];
#pragma unroll
    for (int nt = 0; nt < 4; ++nt) {
        int n = colBase + wc * 64 + nt * 16 + l15;
        asv[nt] = a_src[n];
        adv[nt] = a_dst[n];
    }
#pragma unroll
    for (int mt = 0; mt < 4; ++mt) {
#pragma unroll
        for (int reg = 0; reg < 4; ++reg) {
            int grow = rowBase + wr * 64 + mt * 16 + q * 4 + reg;
            float p1 = acc[mt][0][reg] * asv[0] + acc[mt][1][reg] * asv[1] +
                       acc[mt][2][reg] * asv[2] + acc[mt][3][reg] * asv[3];
            float p2 = acc[mt][0][reg] * adv[0] + acc[mt][1][reg] * adv[1] +
                       acc[mt][2][reg] * adv[2] + acc[mt][3][reg] * adv[3];
            if (grow < N) {
                ushort_t* crow = Hb + (size_t)grow * 256 + colBase + wc * 64 + l15;
#pragma unroll
                for (int nt = 0; nt < 4; ++nt) crow[nt * 16] = f2bf(acc[mt][nt][reg]);
            }
#pragma unroll
            for (int off = 1; off < 16; off <<= 1) {
                p1 += __shfl_xor(p1, off, 64);
                p2 += __shfl_xor(p2, off, 64);
            }
            if (l15 == 0 && grow < N) {
                atomicAdd(&asrc_out[grow], p1);
                atomicAdd(&adst_out[grow], p2);
            }
        }
    }
}

// ---------------- CSR build ----------------
__global__ __launch_bounds__(256) void count_kernel(const int* __restrict__ edst,
                                                    int* __restrict__ deg, int E) {
    int i = blockIdx.x * 256 + threadIdx.x;
    if (i < E) atomicAdd(&deg[edst[i]], 1);
}

__global__ __launch_bounds__(256) void scan1_kernel(const int* __restrict__ deg,
                                                    int* __restrict__ excl,
                                                    int* __restrict__ bsum, int N) {
    __shared__ int tmp[256];
    int tid = threadIdx.x;
    int i = blockIdx.x * 256 + tid;
    int v = (i < N) ? deg[i] : 0;
    tmp[tid] = v;
    __syncthreads();
    for (int off = 1; off < 256; off <<= 1) {
        int t = (tid >= off) ? tmp[tid - off] : 0;
        __syncthreads();
        tmp[tid] += t;
        __syncthreads();
    }
    if (i < N) excl[i] = tmp[tid] - v;
    if (tid == 255) bsum[blockIdx.x] = tmp[255];
}

__global__ __launch_bounds__(256) void scan2_kernel(int* __restrict__ bsum, int nb) {
    __shared__ int tmp[256];
    int tid = threadIdx.x;
    int v = (tid < nb) ? bsum[tid] : 0;
    tmp[tid] = v;
    __syncthreads();
    for (int off = 1; off < 256; off <<= 1) {
        int t = (tid >= off) ? tmp[tid - off] : 0;
        __syncthreads();
        tmp[tid] += t;
        __syncthreads();
    }
    if (tid < nb) bsum[tid] = tmp[tid] - v;
}

__global__ __launch_bounds__(256) void scan3_kernel(const int* __restrict__ excl,
                                                    const int* __restrict__ bsum,
                                                    int* __restrict__ rowptr,
                                                    int* __restrict__ cursor,
                                                    int N, int E) {
    int i = blockIdx.x * 256 + threadIdx.x;
    if (i < N) {
        int v = excl[i] + bsum[blockIdx.x];
        rowptr[i] = v;
        cursor[i] = v;
    }
    if (i == 0) rowptr[N] = E;
}

__global__ __launch_bounds__(256) void scatter_kernel(const int* __restrict__ esrc,
                                                      const int* __restrict__ edst,
                                                      int* __restrict__ cursor,
                                                      int* __restrict__ csr_src, int E) {
    int i = blockIdx.x * 256 + threadIdx.x;
    if (i < E) {
        int d = edst[i];
        int pos = atomicAdd(&cursor[d], 1);
        csr_src[pos] = esrc[i];
    }
}

// ---------------- fused GAT aggregation: one wave per dst node (bf16 h gather) ----------------
// Output written as pre-split hi/lo bf16 (consumed by next GEMM / pool).
__global__ __launch_bounds__(256) void gat_fused_kernel(const ushort_t* __restrict__ hb,
                                                        const float* __restrict__ asrc,
                                                        const float* __restrict__ adst,
                                                        const int* __restrict__ rowptr,
                                                        const int* __restrict__ csr_src,
                                                        const float* __restrict__ bias,
                                                        ushort_t* __restrict__ ohi,
                                                        ushort_t* __restrict__ olo, int N) {
    int wave = threadIdx.x >> 6;
    int lane = threadIdx.x & 63;
    int d = blockIdx.x * 4 + wave;
    if (d >= N) return;

    float ad = adst[d];
    float es = asrc[d] + ad;
    es = es >= 0.f ? es : 0.2f * es;
    float m = es;
    float s = 1.0f;
    float4 acc = ldh4(hb + (size_t)d * 256 + lane * 4);

    int beg = rowptr[d], end = rowptr[d + 1];
    for (int base = beg; base < end; base += 64) {
        int cnt = min(64, end - base);
        int srci = 0;
        float e = -1e30f;
        if (lane < cnt) {
            srci = csr_src[base + lane];
            float v = asrc[srci] + ad;
            e = v >= 0.f ? v : 0.2f * v;
        }
        float cm = e;
#pragma unroll
        for (int off = 32; off > 0; off >>= 1) cm = fmaxf(cm, __shfl_xor(cm, off, 64));
        float mnew = fmaxf(m, cm);
        float scale = __expf(m - mnew);
        s *= scale;
        acc.x *= scale; acc.y *= scale; acc.z *= scale; acc.w *= scale;
        m = mnew;

        int j = 0;
        for (; j + 4 <= cnt; j += 4) {
            float e0 = __shfl(e, j, 64),     e1 = __shfl(e, j + 1, 64);
            float e2 = __shfl(e, j + 2, 64), e3 = __shfl(e, j + 3, 64);
            int s0 = __shfl(srci, j, 64),     s1i = __shfl(srci, j + 1, 64);
            int s2i = __shfl(srci, j + 2, 64), s3i = __shfl(srci, j + 3, 64);
            float4 hv0 = ldh4(hb + (size_t)s0 * 256 + lane * 4);
            float4 hv1 = ldh4(hb + (size_t)s1i * 256 + lane * 4);
            float4 hv2 = ldh4(hb + (size_t)s2i * 256 + lane * 4);
            float4 hv3 = ldh4(hb + (size_t)s3i * 256 + lane * 4);
            float p0 = __expf(e0 - m), p1 = __expf(e1 - m);
            float p2 = __expf(e2 - m), p3 = __expf(e3 - m);
            s += p0 + p1 + p2 + p3;
            acc.x += p0 * hv0.x + p1 * hv1.x + p2 * hv2.x + p3 * hv3.x;
            acc.y += p0 * hv0.y + p1 * hv1.y + p2 * hv2.y + p3 * hv3.y;
            acc.z += p0 * hv0.z + p1 * hv1.z + p2 * hv2.z + p3 * hv3.z;
            acc.w += p0 * hv0.w + p1 * hv1.w + p2 * hv2.w + p3 * hv3.w;
        }
        for (; j < cnt; ++j) {
            float ej = __shfl(e, j, 64);
            int sj = __shfl(srci, j, 64);
            float p = __expf(ej - m);
            float4 hv = ldh4(hb + (size_t)sj * 256 + lane * 4);
            s += p;
            acc.x += p * hv.x; acc.y += p * hv.y; acc.z += p * hv.z; acc.w += p * hv.w;
        }
    }
    float inv = 1.0f / s;
    float4 bv = *(const float4*)(bias + lane * 4);
    float ox = fmaxf(acc.x * inv + bv.x, 0.f);
    float oy = fmaxf(acc.y * inv + bv.y, 0.f);
    float oz = fmaxf(acc.z * inv + bv.z, 0.f);
    float ow = fmaxf(acc.w * inv + bv.w, 0.f);
    ushort4v hv, lv;
    hv.x = f2bf(ox); lv.x = f2bf(ox - bf2f(hv.x));
    hv.y = f2bf(oy); lv.y = f2bf(oy - bf2f(hv.y));
    hv.z = f2bf(oz); lv.z = f2bf(oz - bf2f(hv.z));
    hv.w = f2bf(ow); lv.w = f2bf(ow - bf2f(hv.w));
    *(ushort4v*)(ohi + (size_t)d * 256 + lane * 4) = hv;
    *(ushort4v*)(olo + (size_t)d * 256 + lane * 4) = lv;
}

// ---------------- fused mean pool + FC + softmax (batch is sorted) ----------------
__device__ __forceinline__ int lower_bound_i(const int* __restrict__ a, int n, int v) {
    int lo = 0, hi = n;
    while (lo < hi) {
        int mid = (lo + hi) >> 1;
        if (a[mid] < v) lo = mid + 1; else hi = mid;
    }
    return lo;
}

__global__ __launch_bounds__(256) void pool_fc_kernel(const ushort_t* __restrict__ hhi,
                                                      const ushort_t* __restrict__ hlo,
                                                      const int* __restrict__ batch,
                                                      int N,
                                                      const float* __restrict__ Wfc,
                                                      const float* __restrict__ bfc,
                                                      float* __restrict__ out) {
    __shared__ float red0[256];
    __shared__ float red1[256];
    int g = blockIdx.x;
    int c = threadIdx.x;
    int beg = lower_bound_i(batch, N, g);
    int end = lower_bound_i(batch, N, g + 1);
    float sum = 0.f;
    for (int n = beg; n < end; ++n)
        sum += bf2f(hhi[(size_t)n * 256 + c]) + bf2f(hlo[(size_t)n * 256 + c]);
    float cnt = (float)(end - beg);
    float v = sum / fmaxf(cnt, 1.0f);
    red0[c] = v * Wfc[c * 2 + 0];
    red1[c] = v * Wfc[c * 2 + 1];
    __syncthreads();
    for (int off = 128; off > 0; off >>= 1) {
        if (c < off) {
            red0[c] += red0[c + off];
            red1[c] += red1[c + off];
        }
        __syncthreads();
    }
    if (c == 0) {
        float l0 = red0[0] + bfc[0];
        float l1 = red1[0] + bfc[1];
        float mx = fmaxf(l0, l1);
        float e0 = expf(l0 - mx), e1 = expf(l1 - mx);
        float s = e0 + e1;
        out[g * 2 + 0] = e0 / s;
        out[g * 2 + 1] = e1 / s;
    }
}

// ---------------- launch ----------------
extern "C" void kernel_launch(void* const* d_in, const int* in_sizes, int n_in,
                              void* d_out, int out_size, void* d_ws, size_t ws_size,
                              hipStream_t stream) {
    const float* x    = (const float*)d_in[0];
    const int*   eidx = (const int*)d_in[1];
    const int*   batch= (const int*)d_in[2];
    const float* Wl[3]  = {(const float*)d_in[3], (const float*)d_in[7],  (const float*)d_in[11]};
    const float* asl[3] = {(const float*)d_in[4], (const float*)d_in[8],  (const float*)d_in[12]};
    const float* adl[3] = {(const float*)d_in[5], (const float*)d_in[9],  (const float*)d_in[13]};
    const float* bl[3]  = {(const float*)d_in[6], (const float*)d_in[10], (const float*)d_in[14]};
    const float* Wfc = (const float*)d_in[15];
    const float* bfc = (const float*)d_in[16];
    float* out = (float*)d_out;

    const int N   = in_sizes[2];
    const int E   = in_sizes[1] / 2;
    const int DIN = in_sizes[0] / N;   // 128
    const int DH  = 256;
    const int G   = 512;
    const int* esrc = eidx;
    const int* edst = eidx + E;

    char* ws = (char*)d_ws;
    size_t off = 0;
    const size_t featHalf = (size_t)N * DH * sizeof(ushort_t);      // 25.6 MB
    ushort_t* hb     = (ushort_t*)(ws + off); off += featHalf;      // GEMM out (bf16), gather src
    ushort_t* ghi    = (ushort_t*)(ws + off); off += featHalf;      // gat out hi
    ushort_t* glo    = (ushort_t*)(ws + off); off += featHalf;      // gat out lo
    ushort_t* xhi    = (ushort_t*)(ws + off); off += (size_t)N * DIN * sizeof(ushort_t);
    ushort_t* xlo    = (ushort_t*)(ws + off); off += (size_t)N * DIN * sizeof(ushort_t);
    float*    asrc   = (float*)(ws + off); off += (size_t)N * sizeof(float);
    float*    adst   = (float*)(ws + off); off += (size_t)N * sizeof(float);
    int*      deg    = (int*)(ws + off);   off += (size_t)N * sizeof(int);
    int*      excl   = (int*)(ws + off);   off += (size_t)N * sizeof(int);
    int*      rowptr = (int*)(ws + off);   off += (size_t)(N + 1) * sizeof(int);
    int*      cursor = (int*)(ws + off);   off += (size_t)N * sizeof(int);
    int*      bsum   = (int*)(ws + off);   off += 1024;
    int*      csrsrc = (int*)(ws + off);   off += (size_t)E * sizeof(int);
    ushort_t* Bthi   = (ushort_t*)(ws + off); off += (size_t)256 * 256 * sizeof(ushort_t);
    ushort_t* Btlo   = (ushort_t*)(ws + off); off += (size_t)256 * 256 * sizeof(ushort_t);

    const int nbN = (N + 255) / 256;

    // ---- build CSR by dst (graph fixed across layers) ----
    hipMemsetAsync(deg, 0, (size_t)N * sizeof(int), stream);
    count_kernel<<<(E + 255) / 256, 256, 0, stream>>>(edst, deg, E);
    scan1_kernel<<<nbN, 256, 0, stream>>>(deg, excl, bsum, N);
    scan2_kernel<<<1, 256, 0, stream>>>(bsum, nbN);
    scan3_kernel<<<nbN, 256, 0, stream>>>(excl, bsum, rowptr, cursor, N, E);
    scatter_kernel<<<(E + 255) / 256, 256, 0, stream>>>(esrc, edst, cursor, csrsrc, E);

    // ---- pre-split x for layer 0 ----
    xsplit_kernel<<<((size_t)N * DIN + 255) / 256, 256, 0, stream>>>(x, xhi, xlo, N * DIN);

    for (int layer = 0; layer < 3; ++layer) {
        const ushort_t* Ah = (layer == 0) ? xhi : ghi;
        const ushort_t* Al = (layer == 0) ? xlo : glo;
        const int K = (layer == 0) ? DIN : DH;

        hipMemsetAsync(asrc, 0, 2 * (size_t)N * sizeof(float), stream);
        wsplit_kernel<<<K, 256, 0, stream>>>(Wl[layer], Bthi, Btlo, K);

        dim3 ggrid((N + 127) / 128, 2);
        gemm_mfma<<<ggrid, 256, 0, stream>>>(Ah, Al, Bthi, Btlo, hb,
                                             asl[layer], adl[layer], asrc, adst, N, K);

        gat_fused_kernel<<<(N + 3) / 4, 256, 0, stream>>>(hb, asrc, adst, rowptr, csrsrc,
                                                          bl[layer], ghi, glo, N);
    }

    pool_fc_kernel<<<G, 256, 0, stream>>>(ghi, glo, batch, N, Wfc, bfc, out);
}